// Round 5
// baseline (6443.536 us; speedup 1.0000x reference)
//
#include <hip/hip_runtime.h>

// Problem constants (MotionDiscreteAE): B=32, N=2048, D=512, S=2, K=1024, DS=256
#define BN_   65536   // B*N
#define K_    1024
#define DS_   256
#define D_    512

using bf16x8 = __attribute__((ext_vector_type(8))) short;  // 8 bf16 (4 VGPRs)
using f32x4  = __attribute__((ext_vector_type(4))) float;  // MFMA accumulator

// global -> LDS async DMA, 16 B per lane; LDS dest = uniform base + lane*16
#define GLDS16(gsrc, ldst)                                              \
  __builtin_amdgcn_global_load_lds(                                     \
      (const __attribute__((address_space(1))) void*)(gsrc),            \
      (__attribute__((address_space(3))) void*)(ldst), 16, 0, 0)

// fp32 -> bf16 round-to-nearest-even (data is finite, |x| < 8: no carry into sign)
__device__ __forceinline__ short f2bf(float f) {
  unsigned u = __float_as_uint(f);
  unsigned r = u + 0x7FFFu + ((u >> 16) & 1u);
  return (short)(r >> 16);
}
// order-preserving float<->uint for atomicMin over (possibly negative) floats
__device__ __forceinline__ unsigned encf(float x) {
  unsigned u = __float_as_uint(x);
  return (u & 0x80000000u) ? ~u : (u | 0x80000000u);
}
__device__ __forceinline__ float decf(unsigned e) {
  return __uint_as_float((e & 0x80000000u) ? (e & 0x7FFFFFFFu) : ~e);
}

// ---------------------------------------------------------------------------
// Kernel 0: w_sq[s*K + k] = sum_d W[s][k][d]^2  (fp32 chunked)
// ---------------------------------------------------------------------------
__global__ __launch_bounds__(256)
void wsq_kernel(const float* __restrict__ W, float* __restrict__ wsq) {
  const int k = blockIdx.x * 256 + threadIdx.x;  // 0..2047
  const float4* row = (const float4*)(W + (size_t)k * DS_);
  float s0 = 0.f, s1 = 0.f, s2 = 0.f, s3 = 0.f;
#pragma unroll
  for (int i = 0; i < DS_ / 4; ++i) {
    const float4 v = row[i];
    s0 = fmaf(v.x, v.x, s0);
    s1 = fmaf(v.y, v.y, s1);
    s2 = fmaf(v.z, v.z, s2);
    s3 = fmaf(v.w, v.w, s3);
  }
  wsq[k] = (s0 + s1) + (s2 + s3);
}

// ---------------------------------------------------------------------------
// Kernel 0b: xsq = np.sum(x*x,-1) BIT-EXACT numpy-pairwise fp32 (unchanged
// math). Extended (perf-neutral): xabs[q] = sum|x| (margin input, any order),
// qcnt[q] = 0 (candidate-counter init).
// ---------------------------------------------------------------------------
__global__ __launch_bounds__(256)
void xsq_kernel(const float* __restrict__ h, float* __restrict__ xsq,
                float* __restrict__ xabs, unsigned* __restrict__ qcnt) {
  const int idx = blockIdx.x * 256 + threadIdx.x;  // 0..131071
  const int s = idx >> 16;
  const int m = idx & 0xFFFF;
  const float4* x = (const float4*)(h + (size_t)m * D_ + s * DS_);
  float blk[2];
  float sa = 0.f;
#pragma unroll
  for (int b = 0; b < 2; ++b) {
    float r[8];
    {  // t = 0: a[0..7]
      const float4 v0 = x[b * 32 + 0];
      const float4 v1 = x[b * 32 + 1];
      r[0] = __fmul_rn(v0.x, v0.x); r[1] = __fmul_rn(v0.y, v0.y);
      r[2] = __fmul_rn(v0.z, v0.z); r[3] = __fmul_rn(v0.w, v0.w);
      r[4] = __fmul_rn(v1.x, v1.x); r[5] = __fmul_rn(v1.y, v1.y);
      r[6] = __fmul_rn(v1.z, v1.z); r[7] = __fmul_rn(v1.w, v1.w);
      sa += fabsf(v0.x) + fabsf(v0.y) + fabsf(v0.z) + fabsf(v0.w);
      sa += fabsf(v1.x) + fabsf(v1.y) + fabsf(v1.z) + fabsf(v1.w);
    }
    for (int t = 1; t < 16; ++t) {  // a[t*8 + j], j = 0..7 ascending
      const float4 v0 = x[b * 32 + 2 * t];
      const float4 v1 = x[b * 32 + 2 * t + 1];
      r[0] = __fadd_rn(r[0], __fmul_rn(v0.x, v0.x));
      r[1] = __fadd_rn(r[1], __fmul_rn(v0.y, v0.y));
      r[2] = __fadd_rn(r[2], __fmul_rn(v0.z, v0.z));
      r[3] = __fadd_rn(r[3], __fmul_rn(v0.w, v0.w));
      r[4] = __fadd_rn(r[4], __fmul_rn(v1.x, v1.x));
      r[5] = __fadd_rn(r[5], __fmul_rn(v1.y, v1.y));
      r[6] = __fadd_rn(r[6], __fmul_rn(v1.z, v1.z));
      r[7] = __fadd_rn(r[7], __fmul_rn(v1.w, v1.w));
      sa += fabsf(v0.x) + fabsf(v0.y) + fabsf(v0.z) + fabsf(v0.w);
      sa += fabsf(v1.x) + fabsf(v1.y) + fabsf(v1.z) + fabsf(v1.w);
    }
    const float s01 = __fadd_rn(r[0], r[1]);
    const float s23 = __fadd_rn(r[2], r[3]);
    const float s45 = __fadd_rn(r[4], r[5]);
    const float s67 = __fadd_rn(r[6], r[7]);
    blk[b] = __fadd_rn(__fadd_rn(s01, s23), __fadd_rn(s45, s67));
  }
  xsq[idx] = __fadd_rn(blk[0], blk[1]);
  xabs[idx] = sa;
  qcnt[idx] = 0u;
}

// ---------------------------------------------------------------------------
// Kernel 0c: pack h -> xb bf16, layout [slot = (s*8+ds)*4+dg][m][8] so the
// score kernel can DMA A-tiles (64 m x 8 d) as contiguous 1 KiB chunks.
// slot == d/8 (d = s*256+ds*32+dg*8). LDS-transposed for coalesced writes;
// +slot swizzle in the m index avoids the 64-way write conflict.
// ---------------------------------------------------------------------------
__global__ __launch_bounds__(256)
void preph_kernel(const float* __restrict__ h, short* __restrict__ xb) {
  __shared__ __align__(16) short TB[64 * 64 * 8];  // [slot][m][8], 64 KiB
  const int tid = threadIdx.x;
  const int m0 = blockIdx.x * 64;
#pragma unroll
  for (int p = 0; p < 16; ++p) {
    const int m = p * 4 + (tid >> 6);
    const int dcol = (tid & 63) * 8;
    const float4* hp = (const float4*)(h + (size_t)(m0 + m) * D_ + dcol);
    const float4 v0 = hp[0], v1 = hp[1];
    const int slot = tid & 63;  // == dcol >> 3
    bf16x8 o;
    o[0] = f2bf(v0.x); o[1] = f2bf(v0.y); o[2] = f2bf(v0.z); o[3] = f2bf(v0.w);
    o[4] = f2bf(v1.x); o[5] = f2bf(v1.y); o[6] = f2bf(v1.z); o[7] = f2bf(v1.w);
    *(bf16x8*)&TB[(slot * 64 + ((m + slot) & 63)) * 8] = o;
  }
  __syncthreads();
#pragma unroll
  for (int q = 0; q < 16; ++q) {
    const int slot = q * 4 + (tid >> 6);
    const int m = tid & 63;
    *(bf16x8*)(xb + ((size_t)slot * BN_ + m0 + m) * 8) =
        *(const bf16x8*)&TB[(slot * 64 + ((m + slot) & 63)) * 8];
  }
}

// ---------------------------------------------------------------------------
// Kernel 0d: pack W -> wbt bf16, layout [slot = (s*8+ds)*4+dg][k][8] so the
// score kernel can DMA B-tiles (1024 k x 8 d) as contiguous 16 KiB runs.
// ---------------------------------------------------------------------------
__global__ __launch_bounds__(256)
void prepw_kernel(const float* __restrict__ W, short* __restrict__ wbt) {
  const int idx = blockIdx.x * 256 + threadIdx.x;  // 65536 = [s][k][ds][dg]
  const int dg = idx & 3, ds = (idx >> 2) & 7;
  const int k = (idx >> 5) & 1023, s = idx >> 15;
  const float4* wp =
      (const float4*)(W + (size_t)(s * K_ + k) * DS_ + ds * 32 + dg * 8);
  const float4 v0 = wp[0], v1 = wp[1];
  bf16x8 o;
  o[0] = f2bf(v0.x); o[1] = f2bf(v0.y); o[2] = f2bf(v0.z); o[3] = f2bf(v0.w);
  o[4] = f2bf(v1.x); o[5] = f2bf(v1.y); o[6] = f2bf(v1.z); o[7] = f2bf(v1.w);
  *(bf16x8*)(wbt + ((size_t)((s * 8 + ds) * 4 + dg) * K_ + k) * 8) = o;
}

// ---------------------------------------------------------------------------
// Kernel 1: MFMA prefilter. Per (s, m): approx score S_k = wsq_k - 2*bdot_k
// where bdot = bf16(x).bf16(w) accumulated in fp32 by mfma_f32_16x16x32_bf16.
// Certified margin (|w| <= 2^-10, bf16 RNE err <= 2^-8, fp32-accum + D/S
// rounding): |(D_k-D_j) - (S_k-S_j)| <= 3.07e-5*sum|x| + 6.2e-5. Emit every
// k with S_k <= S_min + M_q (M_q = 3.2e-5*xabs + 2e-4) as a candidate; the
// true argmin and all its ties are provably included; expected ~1.9/query.
// Block: 512 thr (8 waves), 64 m x 1024 k, K-loop 8 d-steps of 32;
// wave = (mw 0..1) x (kw 0..3, 256 k), per wave 2x16 frags (acc 128 VGPR).
// LDS 69.9 KiB -> 2 blocks/CU.
// ---------------------------------------------------------------------------
__global__ __launch_bounds__(512, 2)
void score_kernel(const short* __restrict__ xb, const short* __restrict__ wbt,
                  const float* __restrict__ wsq, const float* __restrict__ xabs,
                  unsigned* __restrict__ qcnt, unsigned* __restrict__ qcand) {
  __shared__ __align__(16) short Bl[4 * K_ * 8];  // [dg][k][8], 64 KiB
  __shared__ __align__(16) short Al[4 * 64 * 8];  // [dg][m][8], 4 KiB
  __shared__ unsigned smin[64];
  const int tid = threadIdx.x;
  const int wave = tid >> 6, l = tid & 63;
  const int mw = wave & 1, kw = wave >> 1;
  const int lg = l >> 4, c = l & 15;
  const int m0 = blockIdx.x * 64, s = blockIdx.y;
  if (tid < 64) smin[tid] = 0xFFFFFFFFu;

  const f32x4 z4 = {0.f, 0.f, 0.f, 0.f};
  f32x4 acc[2][16];
#pragma unroll
  for (int fm = 0; fm < 2; ++fm)
#pragma unroll
    for (int fk = 0; fk < 16; ++fk) acc[fm][fk] = z4;

#pragma unroll 1
  for (int ds = 0; ds < 8; ++ds) {
    __syncthreads();  // previous tile fully consumed (also orders smin init)
    {  // stage B: 64 KiB contiguous for (s,ds) = 64 chunks of 1 KiB
      const short* bsrc = wbt + (size_t)((s * 8 + ds) * 4) * K_ * 8;
#pragma unroll
      for (int i = 0; i < 8; ++i) {
        const int n = wave * 8 + i;
        GLDS16(bsrc + n * 512 + l * 8, &Bl[n * 512]);
      }
    }
    if (wave < 4) {  // stage A: 4 chunks of 1 KiB (dg = wave)
      const short* asrc =
          xb + ((size_t)((s * 8 + ds) * 4 + wave) * BN_ + m0) * 8 + l * 8;
      GLDS16(asrc, &Al[wave * 512]);
    }
    asm volatile("s_waitcnt vmcnt(0)" ::: "memory");
    __syncthreads();

    // A-frags: lane l holds A[m = c][d = lg*8 + e]
    const bf16x8 a0 = *(const bf16x8*)&Al[(lg * 64 + mw * 32 + c) * 8];
    const bf16x8 a1 = *(const bf16x8*)&Al[(lg * 64 + mw * 32 + 16 + c) * 8];
#pragma unroll
    for (int fk = 0; fk < 16; ++fk) {
      // B-frag: lane l holds B[d = lg*8 + e][k = c]  (= wb[k][d] row-slice)
      const bf16x8 b =
          *(const bf16x8*)&Bl[(lg * K_ + kw * 256 + fk * 16 + c) * 8];
      acc[0][fk] =
          __builtin_amdgcn_mfma_f32_16x16x32_bf16(a0, b, acc[0][fk], 0, 0, 0);
      acc[1][fk] =
          __builtin_amdgcn_mfma_f32_16x16x32_bf16(a1, b, acc[1][fk], 0, 0, 0);
    }
  }

  // ---- epilogue: fold min, then margin-filter emit ----
  const float* wsq_s = wsq + s * K_;
  float wv[16];
#pragma unroll
  for (int fk = 0; fk < 16; ++fk) wv[fk] = wsq_s[kw * 256 + fk * 16 + c];

#pragma unroll
  for (int fm = 0; fm < 2; ++fm)
#pragma unroll
    for (int r = 0; r < 4; ++r) {
      float lm = 3.4e38f;
#pragma unroll
      for (int fk = 0; fk < 16; ++fk)
        lm = fminf(lm, wv[fk] - 2.0f * acc[fm][fk][r]);
      // C/D layout: row = lg*4 + r (m-local), col = c (k-local)
      atomicMin(&smin[mw * 32 + fm * 16 + lg * 4 + r], encf(lm));
    }
  __syncthreads();
#pragma unroll
  for (int fm = 0; fm < 2; ++fm)
#pragma unroll
    for (int r = 0; r < 4; ++r) {
      const int mloc = mw * 32 + fm * 16 + lg * 4 + r;
      const unsigned qid = (unsigned)(s * BN_ + m0 + mloc);
      const float thr =
          decf(smin[mloc]) + (3.2e-5f * xabs[qid] + 2.0e-4f);
#pragma unroll
      for (int fk = 0; fk < 16; ++fk) {
        const float S = wv[fk] - 2.0f * acc[fm][fk][r];
        if (S <= thr) {
          const unsigned slot = atomicAdd(&qcnt[qid], 1u);
          if (slot < 16u)
            qcand[qid * 16u + slot] = (unsigned)(kw * 256 + fk * 16 + c);
        }
      }
    }
}

// ---------------------------------------------------------------------------
// Exact distance, BIT-IDENTICAL to the R4 chain: 8 chunks of 32-d serial FMA
// (d ascending), acc += acct per chunk, D = fl(fl(Xq+wsq) - 2*acc).
// ---------------------------------------------------------------------------
__device__ __forceinline__ float exactD(const float* __restrict__ x,
                                        const float* __restrict__ w,
                                        float Xq, float wsqk) {
  float acc = 0.f;
#pragma unroll
  for (int cch = 0; cch < 8; ++cch) {
    float t = 0.f;
    const float4* x4 = (const float4*)(x + cch * 32);
    const float4* w4 = (const float4*)(w + cch * 32);
#pragma unroll
    for (int g = 0; g < 8; ++g) {
      const float4 a = x4[g];
      const float4 b = w4[g];
      t = fmaf(a.x, b.x, t);
      t = fmaf(a.y, b.y, t);
      t = fmaf(a.z, b.z, t);
      t = fmaf(a.w, b.w, t);
    }
    acc += t;
  }
  const float t1 = __fadd_rn(Xq, wsqk);
  return __fsub_rn(t1, 2.0f * acc);
}

// ---------------------------------------------------------------------------
// Kernel 2: exact rescore of candidates, one query per thread. Lexicographic
// (D, k) min == np.argmin (candidates unsorted -> explicit tie compare; the
// >16-candidate overflow path full-scans k ascending with strict <).
// Also writes the per-block loss partials (sum of winning D).
// ---------------------------------------------------------------------------
__global__ __launch_bounds__(256)
void rescore_kernel(const float* __restrict__ h, const float* __restrict__ W,
                    const float* __restrict__ wsq,
                    const float* __restrict__ xsq,
                    const unsigned* __restrict__ qcnt,
                    const unsigned* __restrict__ qcand,
                    int* __restrict__ ids, float* __restrict__ partials) {
  const int tid = threadIdx.x;
  const int qid = blockIdx.x * 256 + tid;  // 0..131071
  const int s = qid >> 16, m = qid & 0xFFFF;
  const float* xr = h + (size_t)m * D_ + s * DS_;
  const float* Wb = W + (size_t)s * K_ * DS_;
  const float* wsq_s = wsq + s * K_;
  const float Xq = xsq[qid];
  const unsigned n = qcnt[qid];
  float bD = 3.4e38f;
  int bk = 0x7fffffff;
  if (n >= 1u && n <= 16u) {
    for (unsigned t = 0; t < n; ++t) {
      const int k = (int)qcand[qid * 16u + t];
      const float D = exactD(xr, Wb + (size_t)k * DS_, Xq, wsq_s[k]);
      if (D < bD || (D == bD && k < bk)) { bD = D; bk = k; }
    }
  } else {  // overflow (statistically ~never) or empty (impossible): full scan
    for (int k = 0; k < K_; ++k) {
      const float D = exactD(xr, Wb + (size_t)k * DS_, Xq, wsq_s[k]);
      if (D < bD) { bD = D; bk = k; }
    }
  }
  ids[qid] = bk;
  __shared__ float red[256];
  red[tid] = bD;
  __syncthreads();
  for (int off = 128; off > 0; off >>= 1) {
    if (tid < off) red[tid] += red[tid + off];
    __syncthreads();
  }
  if (tid == 0) partials[blockIdx.x] = red[0];
}

// ---------------------------------------------------------------------------
// Kernel 3: z[m][d] = W[s][ids[s][m]][d mod 256];  out_ids[m] = id0 + 1024*id1
// ---------------------------------------------------------------------------
__global__ __launch_bounds__(256)
void gather_kernel(const float* __restrict__ W, const int* __restrict__ ids,
                   float* __restrict__ out) {
  const int tid = threadIdx.x;
  float* out_ids = out + (size_t)BN_ * D_;
#pragma unroll
  for (int it = 0; it < 4; ++it) {
    const size_t i4 = (size_t)it * 2097152 + (size_t)blockIdx.x * 256 + tid;
    const size_t e  = i4 * 4;               // element index into [BN, 512]
    const int m  = (int)(e >> 9);
    const int d  = (int)(e & 511);
    const int s  = d >> 8;
    const int dd = d & 255;
    const int id = ids[s * BN_ + m];
    const float4 z = *(const float4*)(W + ((size_t)(s * K_ + id)) * DS_ + dd);
    *(float4*)(out + e) = z;
    if (d == 0) {  // one thread per m writes the packed id (as float value)
      const int id1 = ids[BN_ + m];
      out_ids[m] = (float)(id + (id1 << 10));
    }
  }
}

// ---------------------------------------------------------------------------
// Kernel 4: vq_total = 1.25 * sum(partials[0..512)) / (BN*DS)
// ---------------------------------------------------------------------------
__global__ __launch_bounds__(256)
void finalize_kernel(const float* __restrict__ partials,
                     float* __restrict__ out_vq) {
  __shared__ float red[256];
  const int tid = threadIdx.x;
  float s = 0.f;
  for (int i = tid; i < 512; i += 256) s += partials[i];
  red[tid] = s;
  __syncthreads();
  for (int off = 128; off > 0; off >>= 1) {
    if (tid < off) red[tid] += red[tid + off];
    __syncthreads();
  }
  if (tid == 0) out_vq[0] = red[0] * (1.25f / 16777216.f);
}

// ---------------------------------------------------------------------------
// Scratch: big buffers live in the z-region of `out` (33.5M floats), which is
// only overwritten by gather_kernel AFTER rescore consumed them:
//   xb    @ out[0)          : 33,554,432 shorts (bf16 h, tiled)
//   wbt   @ out[16777216)   :    524,288 shorts (bf16 W, tiled)
//   xabs  @ out[17039360)   :    131,072 floats
//   qcnt  @ out[17170432)   :    131,072 uint32
//   qcand @ out[17301504)   :  2,097,152 uint32 (16 slots/query)
// ws keeps the previous rounds' footprint: wsq | partials | ids | xsq.
// ---------------------------------------------------------------------------
extern "C" void kernel_launch(void* const* d_in, const int* in_sizes, int n_in,
                              void* d_out, int out_size, void* d_ws,
                              size_t ws_size, hipStream_t stream) {
  const float* h = (const float*)d_in[0];  // [BN, 512]
  const float* W = (const float*)d_in[1];  // [2, 1024, 256]
  float* out  = (float*)d_out;             // z | ids(as float) | vq_total
  float* wsf  = (float*)d_ws;
  float* wsq      = wsf;                   // 2048 floats
  float* partials = wsf + 2048;            // 2048 floats (512 used)
  int*   ids      = (int*)(wsf + 4096);    // 131072 ints
  float* xsq      = wsf + 4096 + 131072;   // 131072 floats

  short*    xb    = (short*)out;
  short*    wbt   = (short*)(out + 16777216);
  float*    xabs  = out + 17039360;
  unsigned* qcnt  = (unsigned*)(out + 17170432);
  unsigned* qcand = (unsigned*)(out + 17301504);

  wsq_kernel<<<8, 256, 0, stream>>>(W, wsq);
  xsq_kernel<<<512, 256, 0, stream>>>(h, xsq, xabs, qcnt);
  prepw_kernel<<<256, 256, 0, stream>>>(W, wbt);
  preph_kernel<<<1024, 256, 0, stream>>>(h, xb);
  score_kernel<<<dim3(1024, 2), 512, 0, stream>>>(xb, wbt, wsq, xabs, qcnt,
                                                  qcand);
  rescore_kernel<<<512, 256, 0, stream>>>(h, W, wsq, xsq, qcnt, qcand, ids,
                                          partials);
  gather_kernel<<<8192, 256, 0, stream>>>(W, ids, out);
  finalize_kernel<<<1, 256, 0, stream>>>(partials,
                                         out + (size_t)BN_ * D_ + BN_);
}

// Round 7
// 903.713 us; speedup vs baseline: 7.1301x; 7.1301x over previous
//
#include <hip/hip_runtime.h>

// Problem constants (MotionDiscreteAE): B=32, N=2048, D=512, S=2, K=1024, DS=256
#define BN_   65536   // B*N
#define K_    1024
#define DS_   256
#define D_    512

using bf16x8 = __attribute__((ext_vector_type(8))) short;  // 8 bf16 (4 VGPRs)
using f32x4  = __attribute__((ext_vector_type(4))) float;  // MFMA accumulator

// fp32 -> bf16 round-to-nearest-even (finite data, |x| small: no sign carry)
__device__ __forceinline__ short f2bf(float f) {
  unsigned u = __float_as_uint(f);
  unsigned r = u + 0x7FFFu + ((u >> 16) & 1u);
  return (short)(r >> 16);
}
// order-preserving float<->uint for unsigned min over (possibly negative) floats
__device__ __forceinline__ unsigned encf(float x) {
  unsigned u = __float_as_uint(x);
  return (u & 0x80000000u) ? ~u : (u | 0x80000000u);
}
__device__ __forceinline__ float decf(unsigned e) {
  return __uint_as_float((e & 0x80000000u) ? (e & 0x7FFFFFFFu) : ~e);
}

// ---------------------------------------------------------------------------
// Kernel 0: w_sq[s*K + k] = sum_d W[s][k][d]^2  (fp32 chunked)
// ---------------------------------------------------------------------------
__global__ __launch_bounds__(256)
void wsq_kernel(const float* __restrict__ W, float* __restrict__ wsq) {
  const int k = blockIdx.x * 256 + threadIdx.x;  // 0..2047
  const float4* row = (const float4*)(W + (size_t)k * DS_);
  float s0 = 0.f, s1 = 0.f, s2 = 0.f, s3 = 0.f;
#pragma unroll
  for (int i = 0; i < DS_ / 4; ++i) {
    const float4 v = row[i];
    s0 = fmaf(v.x, v.x, s0);
    s1 = fmaf(v.y, v.y, s1);
    s2 = fmaf(v.z, v.z, s2);
    s3 = fmaf(v.w, v.w, s3);
  }
  wsq[k] = (s0 + s1) + (s2 + s3);
}

// ---------------------------------------------------------------------------
// Kernel 0b: xsq = np.sum(x*x,-1) BIT-EXACT numpy-pairwise fp32 (verified).
// ---------------------------------------------------------------------------
__global__ __launch_bounds__(256)
void xsq_kernel(const float* __restrict__ h, float* __restrict__ xsq) {
  const int idx = blockIdx.x * 256 + threadIdx.x;  // 0..131071
  const int s = idx >> 16;
  const int m = idx & 0xFFFF;
  const float4* x = (const float4*)(h + (size_t)m * D_ + s * DS_);
  float blk[2];
#pragma unroll
  for (int b = 0; b < 2; ++b) {
    float r[8];
    {
      const float4 v0 = x[b * 32 + 0];
      const float4 v1 = x[b * 32 + 1];
      r[0] = __fmul_rn(v0.x, v0.x); r[1] = __fmul_rn(v0.y, v0.y);
      r[2] = __fmul_rn(v0.z, v0.z); r[3] = __fmul_rn(v0.w, v0.w);
      r[4] = __fmul_rn(v1.x, v1.x); r[5] = __fmul_rn(v1.y, v1.y);
      r[6] = __fmul_rn(v1.z, v1.z); r[7] = __fmul_rn(v1.w, v1.w);
    }
    for (int t = 1; t < 16; ++t) {
      const float4 v0 = x[b * 32 + 2 * t];
      const float4 v1 = x[b * 32 + 2 * t + 1];
      r[0] = __fadd_rn(r[0], __fmul_rn(v0.x, v0.x));
      r[1] = __fadd_rn(r[1], __fmul_rn(v0.y, v0.y));
      r[2] = __fadd_rn(r[2], __fmul_rn(v0.z, v0.z));
      r[3] = __fadd_rn(r[3], __fmul_rn(v0.w, v0.w));
      r[4] = __fadd_rn(r[4], __fmul_rn(v1.x, v1.x));
      r[5] = __fadd_rn(r[5], __fmul_rn(v1.y, v1.y));
      r[6] = __fadd_rn(r[6], __fmul_rn(v1.z, v1.z));
      r[7] = __fadd_rn(r[7], __fmul_rn(v1.w, v1.w));
    }
    const float s01 = __fadd_rn(r[0], r[1]);
    const float s23 = __fadd_rn(r[2], r[3]);
    const float s45 = __fadd_rn(r[4], r[5]);
    const float s67 = __fadd_rn(r[6], r[7]);
    blk[b] = __fadd_rn(__fadd_rn(s01, s23), __fadd_rn(s45, s67));
  }
  xsq[idx] = __fadd_rn(blk[0], blk[1]);
}

// ---------------------------------------------------------------------------
// Kernel 0c: pack h -> xb bf16, layout [slot = d/8][m][8] (slot 0..63).
// ---------------------------------------------------------------------------
__global__ __launch_bounds__(256)
void preph_kernel(const float* __restrict__ h, short* __restrict__ xb) {
  __shared__ __align__(16) short TB[64 * 64 * 8];  // [slot][m][8], 64 KiB
  const int tid = threadIdx.x;
  const int m0 = blockIdx.x * 64;
#pragma unroll
  for (int p = 0; p < 16; ++p) {
    const int m = p * 4 + (tid >> 6);
    const int dcol = (tid & 63) * 8;
    const float4* hp = (const float4*)(h + (size_t)(m0 + m) * D_ + dcol);
    const float4 v0 = hp[0], v1 = hp[1];
    const int slot = tid & 63;  // == dcol >> 3
    bf16x8 o;
    o[0] = f2bf(v0.x); o[1] = f2bf(v0.y); o[2] = f2bf(v0.z); o[3] = f2bf(v0.w);
    o[4] = f2bf(v1.x); o[5] = f2bf(v1.y); o[6] = f2bf(v1.z); o[7] = f2bf(v1.w);
    *(bf16x8*)&TB[(slot * 64 + ((m + slot) & 63)) * 8] = o;
  }
  __syncthreads();
#pragma unroll
  for (int q = 0; q < 16; ++q) {
    const int slot = q * 4 + (tid >> 6);
    const int m = tid & 63;
    *(bf16x8*)(xb + ((size_t)slot * BN_ + m0 + m) * 8) =
        *(const bf16x8*)&TB[(slot * 64 + ((m + slot) & 63)) * 8];
  }
}

// ---------------------------------------------------------------------------
// Kernel 0d: pack W -> wbt bf16, layout [slot = (s*8+ds)*4+dg][k][8].
// ---------------------------------------------------------------------------
__global__ __launch_bounds__(256)
void prepw_kernel(const float* __restrict__ W, short* __restrict__ wbt) {
  const int idx = blockIdx.x * 256 + threadIdx.x;  // 65536 = [s][k][ds][dg]
  const int dg = idx & 3, ds = (idx >> 2) & 7;
  const int k = (idx >> 5) & 1023, s = idx >> 15;
  const float4* wp =
      (const float4*)(W + (size_t)(s * K_ + k) * DS_ + ds * 32 + dg * 8);
  const float4 v0 = wp[0], v1 = wp[1];
  bf16x8 o;
  o[0] = f2bf(v0.x); o[1] = f2bf(v0.y); o[2] = f2bf(v0.z); o[3] = f2bf(v0.w);
  o[4] = f2bf(v1.x); o[5] = f2bf(v1.y); o[6] = f2bf(v1.z); o[7] = f2bf(v1.w);
  *(bf16x8*)(wbt + ((size_t)((s * 8 + ds) * 4 + dg) * K_ + k) * 8) = o;
}

// ---------------------------------------------------------------------------
// Exact distance, BIT-IDENTICAL to the verified chain (R9's full scans passed
// through this exact op order): 8 chunks of 32-d serial FMA, acc += t,
// D = fl(fl(Xq+wsq) - 2*acc). x comes from the granule-XOR-swizzled LDS tile.
// ---------------------------------------------------------------------------
__device__ __forceinline__ float exactD_lds(const float* __restrict__ XF,
                                            int q, const float* __restrict__ w,
                                            float Xq, float wsqk) {
  float acc = 0.f;
#pragma unroll
  for (int cch = 0; cch < 8; ++cch) {
    float t = 0.f;
#pragma unroll
    for (int gg = 0; gg < 8; ++gg) {
      const int g = cch * 8 + gg;
      const float4 a = *(const float4*)(XF + q * 256 + ((g ^ q) & 63) * 4);
      const float4 b = *(const float4*)(w + g * 4);
      t = fmaf(a.x, b.x, t);
      t = fmaf(a.y, b.y, t);
      t = fmaf(a.z, b.z, t);
      t = fmaf(a.w, b.w, t);
    }
    acc += t;
  }
  const float t1 = __fadd_rn(Xq, wsqk);
  return __fsub_rn(t1, 2.0f * acc);
}

// ---------------------------------------------------------------------------
// Kernel 1 (fused): MFMA prefilter + in-block exact rescore.
// Approx score S_k = wsq_k - 2*bf16dot (fp32 accum). Certified margin
// (|w|<=2^-10, bf16 RNE u<=2^-8 on both operands, fp32-chain + D/S rounding,
// 2x slack): any k with exact D_k <= exact D_min has S_k <= S_min + M,
// M = 3.2e-5*sum|x| + 2e-4 (~6.7e-3; expected extra candidates ~1/query).
// Candidates collected in LDS, exactly rescored in-block (fp32 x tile reuses
// the dead B-buffer). Overflow (>16 cands) -> cooperative in-block full scan.
// Correctness NEVER depends on S. All reductions 32-bit two-phase
// (atomicMin bmin -> barrier -> tie-break atomicMin bidx): lexicographic
// (D, lowest k) == np.argmin. No 64-bit atomics (R10 hardening).
// Block 512 thr (8 waves), 64 queries x 1024 codes; wave = (mw,kw);
// per wave 2x16 16x16x32 frags. LDS ~73 KiB, VGPR ~230 -> 1 block/CU.
// ---------------------------------------------------------------------------
__global__ __launch_bounds__(512, 2)
void score_kernel(const short* __restrict__ xb, const short* __restrict__ wbt,
                  const float* __restrict__ h, const float* __restrict__ W,
                  const float* __restrict__ wsq, const float* __restrict__ xsq,
                  int* __restrict__ ids, float* __restrict__ partials) {
  __shared__ __align__(16) short Bl[4 * K_ * 8];  // 64 KiB; reused as XF fp32
  __shared__ __align__(16) short Al[4 * 64 * 8];  // 4 KiB
  __shared__ unsigned smin[64];
  __shared__ unsigned ccnt[64];
  __shared__ unsigned bmin[64];
  __shared__ unsigned bidx[64];
  __shared__ unsigned short cand[64][16];
  __shared__ float xab[64];
  __shared__ unsigned ovf[64];
  __shared__ unsigned novf;

  const int tid = threadIdx.x;
  const int wave = tid >> 6, l = tid & 63;
  const int mw = wave & 1, kw = wave >> 1;
  const int lg = l >> 4, c = l & 15;
  const int m0 = blockIdx.x * 64, s = blockIdx.y;

  if (tid < 64) smin[tid] = 0xFFFFFFFFu;

  const f32x4 z4 = {0.f, 0.f, 0.f, 0.f};
  f32x4 acc[2][16];
#pragma unroll
  for (int fm = 0; fm < 2; ++fm)
#pragma unroll
    for (int fk = 0; fk < 16; ++fk) acc[fm][fk] = z4;

  // ---- MFMA loop: 8 d-steps of 32, register-staged LDS tiles ----
#pragma unroll 1
  for (int ds = 0; ds < 8; ++ds) {
    uint4 breg[8];
    const char* bsrc = (const char*)wbt + ((size_t)(s * 8 + ds) << 16);
#pragma unroll
    for (int i = 0; i < 8; ++i)
      breg[i] = *(const uint4*)(bsrc + (i << 13) + (tid << 4));
    uint4 areg;
    if (tid < 256) {
      const int dg = tid >> 6, ml = tid & 63;
      areg = *(const uint4*)((const char*)xb +
          (((size_t)((s * 8 + ds) * 4 + dg) * BN_ + m0 + ml) << 4));
    }
    __syncthreads();  // previous tile fully consumed
#pragma unroll
    for (int i = 0; i < 8; ++i)
      *(uint4*)((char*)Bl + (i << 13) + (tid << 4)) = breg[i];
    if (tid < 256) *(uint4*)((char*)Al + (tid << 4)) = areg;
    __syncthreads();  // tile ready

    // A-frag: lane (lg,c) holds A[m = mw*32(+16) + c][kdim = lg*8 + e]
    const bf16x8 a0 = *(const bf16x8*)&Al[(lg * 64 + mw * 32 + c) * 8];
    const bf16x8 a1 = *(const bf16x8*)&Al[(lg * 64 + mw * 32 + 16 + c) * 8];
#pragma unroll
    for (int fk = 0; fk < 16; ++fk) {
      // B-frag: lane (lg,c) holds B[kdim = lg*8 + e][code = kw*256+fk*16+c]
      const bf16x8 b =
          *(const bf16x8*)&Bl[((lg << 10) + kw * 256 + fk * 16 + c) * 8];
      acc[0][fk] =
          __builtin_amdgcn_mfma_f32_16x16x32_bf16(a0, b, acc[0][fk], 0, 0, 0);
      acc[1][fk] =
          __builtin_amdgcn_mfma_f32_16x16x32_bf16(a1, b, acc[1][fk], 0, 0, 0);
    }
  }

  // ---- fold per-query S-min (C/D: row = lg*4 + r, col = c) ----
  const float* __restrict__ wsq_s = wsq + s * K_;
  float wv[16];
#pragma unroll
  for (int fk = 0; fk < 16; ++fk) wv[fk] = wsq_s[kw * 256 + fk * 16 + c];
#pragma unroll
  for (int fm = 0; fm < 2; ++fm)
#pragma unroll
    for (int r = 0; r < 4; ++r) {
      float lm = 3.4e38f;
#pragma unroll
      for (int fk = 0; fk < 16; ++fk)
        lm = fminf(lm, wv[fk] - 2.0f * acc[fm][fk][r]);
      atomicMin(&smin[mw * 32 + fm * 16 + lg * 4 + r], encf(lm));
    }
  __syncthreads();  // all Bl reads done; smin complete

  // ---- stage fp32 x tile over Bl (granule-XOR swizzle); init state ----
  float* XF = (float*)Bl;
  if (tid < 64) {
    ccnt[tid] = 0u;
    bmin[tid] = 0xFFFFFFFFu;
    bidx[tid] = 0x7FFFFFFFu;
  }
  if (tid == 0) novf = 0u;
#pragma unroll
  for (int it = 0; it < 8; ++it) {
    const int idx = it * 512 + tid;  // 0..4095
    const int q = idx >> 6, g = idx & 63;
    const float4 v =
        *(const float4*)(h + (size_t)(m0 + q) * D_ + s * DS_ + g * 4);
    *(float4*)(XF + q * 256 + ((g ^ q) & 63) * 4) = v;
  }
  __syncthreads();  // XF + counters ready
  if (tid < 64) {
    float a = 0.f;
    for (int g = 0; g < 64; ++g) {
      const float4 v = *(const float4*)(XF + tid * 256 + ((g ^ tid) & 63) * 4);
      a += fabsf(v.x) + fabsf(v.y) + fabsf(v.z) + fabsf(v.w);
    }
    xab[tid] = a;
  }
  __syncthreads();  // xab ready

  // ---- margin-filter emit into LDS candidate lists ----
#pragma unroll
  for (int fm = 0; fm < 2; ++fm)
#pragma unroll
    for (int r = 0; r < 4; ++r) {
      const int mloc = mw * 32 + fm * 16 + lg * 4 + r;
      const float thr = decf(smin[mloc]) + (3.2e-5f * xab[mloc] + 2.0e-4f);
#pragma unroll
      for (int fk = 0; fk < 16; ++fk) {
        const float S = wv[fk] - 2.0f * acc[fm][fk][r];
        if (S <= thr) {
          const unsigned slot = atomicAdd(&ccnt[mloc], 1u);
          if (slot < 16u)
            cand[mloc][slot] = (unsigned short)(kw * 256 + fk * 16 + c);
        }
      }
    }
  __syncthreads();  // cand/ccnt complete

  // ---- overflow detection ----
  if (tid < 64 && ccnt[tid] > 16u) ovf[atomicAdd(&novf, 1u)] = (unsigned)tid;

  // ---- candidate exact rescore, phase A (min D), all 32-bit ----
  const float* __restrict__ Wb = W + (size_t)s * K_ * DS_;
  float dA = 0.f, dB = 0.f;
  int kA = -1, qA = -1, kB = -1, qB = -1;
  {
    int q = tid >> 4, sl = tid & 15;            // queries 0..31
    unsigned n = ccnt[q];
    if (n <= 16u && (unsigned)sl < n) {
      kA = (int)cand[q][sl]; qA = q;
      dA = exactD_lds(XF, q, Wb + (size_t)kA * DS_,
                      xsq[s * BN_ + m0 + q], wsq_s[kA]);
      atomicMin(&bmin[q], encf(dA));
    }
    q = 32 + (tid >> 4);                        // queries 32..63
    n = ccnt[q];
    if (n <= 16u && (unsigned)sl < n) {
      kB = (int)cand[q][sl]; qB = q;
      dB = exactD_lds(XF, q, Wb + (size_t)kB * DS_,
                      xsq[s * BN_ + m0 + q], wsq_s[kB]);
      atomicMin(&bmin[q], encf(dB));
    }
  }
  __syncthreads();  // bmin complete; novf/ovf visible
  // phase B: tie-break lowest k among D == bmin
  if (qA >= 0 && encf(dA) == bmin[qA]) atomicMin(&bidx[qA], (unsigned)kA);
  if (qB >= 0 && encf(dB) == bmin[qB]) atomicMin(&bidx[qB], (unsigned)kB);
  __syncthreads();

  // ---- overflow queries: cooperative exact full scan (two-phase) ----
  for (unsigned o = 0; o < novf; ++o) {
    const int q = (int)ovf[o];
    const float Xq = xsq[s * BN_ + m0 + q];
    float bD = 3.4e38f;
    int bK = 0x7FFFFFFF;
    for (int k = tid; k < K_; k += 512) {  // ascending: strict < keeps low k
      const float D = exactD_lds(XF, q, Wb + (size_t)k * DS_, Xq, wsq_s[k]);
      if (D < bD) { bD = D; bK = k; }
    }
    atomicMin(&bmin[q], encf(bD));
    __syncthreads();
    if (bK != 0x7FFFFFFF && encf(bD) == bmin[q])
      atomicMin(&bidx[q], (unsigned)bK);
    __syncthreads();
  }

  // ---- winners: lexicographic (D, k) == np.argmin; loss partial ----
  if (tid < 64) {
    ids[s * BN_ + m0 + tid] = (int)bidx[tid];
    float v = decf(bmin[tid]);  // quantized ||x - w_best||^2
#pragma unroll
    for (int off = 32; off > 0; off >>= 1) v += __shfl_down(v, off);
    if (tid == 0) partials[s * 1024 + blockIdx.x] = v;
  }
}

// ---------------------------------------------------------------------------
// Kernel 2: z[m][d] = W[s][ids[s][m]][d mod 256];  out_ids[m] = id0 + 1024*id1
// ---------------------------------------------------------------------------
__global__ __launch_bounds__(256)
void gather_kernel(const float* __restrict__ W, const int* __restrict__ ids,
                   float* __restrict__ out) {
  const int tid = threadIdx.x;
  float* out_ids = out + (size_t)BN_ * D_;
#pragma unroll
  for (int it = 0; it < 4; ++it) {
    const size_t i4 = (size_t)it * 2097152 + (size_t)blockIdx.x * 256 + tid;
    const size_t e  = i4 * 4;               // element index into [BN, 512]
    const int m  = (int)(e >> 9);
    const int d  = (int)(e & 511);
    const int s  = d >> 8;
    const int dd = d & 255;
    const int id = ids[s * BN_ + m];
    const float4 z = *(const float4*)(W + ((size_t)(s * K_ + id)) * DS_ + dd);
    *(float4*)(out + e) = z;
    if (d == 0) {
      const int id1 = ids[BN_ + m];
      out_ids[m] = (float)(id + (id1 << 10));
    }
  }
}

// ---------------------------------------------------------------------------
// Kernel 3: vq_total = 1.25 * sum(partials[0..2048)) / (BN*DS)
// ---------------------------------------------------------------------------
__global__ __launch_bounds__(256)
void finalize_kernel(const float* __restrict__ partials,
                     float* __restrict__ out_vq) {
  __shared__ float red[256];
  const int tid = threadIdx.x;
  float s = 0.f;
  for (int i = tid; i < 2048; i += 256) s += partials[i];
  red[tid] = s;
  __syncthreads();
  for (int off = 128; off > 0; off >>= 1) {
    if (tid < off) red[tid] += red[tid + off];
    __syncthreads();
  }
  if (tid == 0) out_vq[0] = red[0] * (1.25f / 16777216.f);
}

// ---------------------------------------------------------------------------
// Scratch: xb/wbt live in the z-region of `out` (written by prep kernels,
// consumed by score, fully overwritten by gather afterwards):
//   xb  @ out[0)        : 33,554,432 shorts (bf16 h, [slot][m][8])
//   wbt @ out[16777216) :    524,288 shorts (bf16 W, [slot][k][8])
// ws: wsq | partials | ids | xsq  (as in all prior rounds).
// ---------------------------------------------------------------------------
extern "C" void kernel_launch(void* const* d_in, const int* in_sizes, int n_in,
                              void* d_out, int out_size, void* d_ws,
                              size_t ws_size, hipStream_t stream) {
  const float* h = (const float*)d_in[0];  // [BN, 512]
  const float* W = (const float*)d_in[1];  // [2, 1024, 256]
  float* out  = (float*)d_out;             // z | ids(as float) | vq_total
  float* wsf  = (float*)d_ws;
  float* wsq      = wsf;                   // 2048 floats
  float* partials = wsf + 2048;            // 2048 floats
  int*   ids      = (int*)(wsf + 4096);    // 131072 ints
  float* xsq      = wsf + 4096 + 131072;   // 131072 floats

  short* xb  = (short*)out;
  short* wbt = (short*)(out + 16777216);

  wsq_kernel<<<8, 256, 0, stream>>>(W, wsq);
  xsq_kernel<<<512, 256, 0, stream>>>(h, xsq);
  prepw_kernel<<<256, 256, 0, stream>>>(W, wbt);
  preph_kernel<<<1024, 256, 0, stream>>>(h, xb);
  score_kernel<<<dim3(1024, 2), 512, 0, stream>>>(xb, wbt, h, W, wsq, xsq,
                                                  ids, partials);
  gather_kernel<<<8192, 256, 0, stream>>>(W, ids, out);
  finalize_kernel<<<1, 256, 0, stream>>>(partials,
                                         out + (size_t)BN_ * D_ + BN_);
}